// Round 14
// baseline (240.628 us; speedup 1.0000x reference)
//
#include <hip/hip_runtime.h>

// ---------------------------------------------------------------------------
// RelationalTransformer: B=32 T=4 L=1024 D=1024 H=8 Hd=128 N=15
// out = edge_logits (32*15*15*18 = 129600) ++ energy (32)   [fp32]
//
// R14: (a) sv_k fuses sgemm (512 blocks) + cvtT (8192 blocks) -> the two
// independent v_f consumers run concurrently in one launch. (b) tail_k
// energy blocks = 1/batch computing all 256 units + in-LDS final reduce
// (energy3 + hidr eliminated). 12 -> 10 dispatches. All bit-exact vs R13.
// ---------------------------------------------------------------------------

typedef __attribute__((ext_vector_type(8))) short bf16x8;   // 8 bf16 in 4 VGPRs
typedef __attribute__((ext_vector_type(4))) float f32x4;

__device__ __forceinline__ unsigned short f2bf(float f) {   // RNE float->bf16
    unsigned int u = __float_as_uint(f);
    u = u + 0x7FFFu + ((u >> 16) & 1u);
    return (unsigned short)(u >> 16);
}

// async global->LDS, 16B per lane, dest = wave-uniform base + lane*16
__device__ __forceinline__ void gload_lds16(const void* g, void* l) {
    __builtin_amdgcn_global_load_lds(
        (const __attribute__((address_space(1))) void*)g,
        (__attribute__((address_space(3))) void*)l,
        16, 0, 0);
}

// ---------------- PV bf16 MFMA GEMM (64x128 tile, 4 waves): C = A @ B^T, bf16 out
__global__ __launch_bounds__(256) void bfgemm_k(
    const unsigned short* __restrict__ A, const unsigned short* __restrict__ B,
    unsigned short* __restrict__ C, int M, long sA, long sB, long sC)
{
    const int b  = blockIdx.z;
    const int m0 = blockIdx.y * 64;
    const int n0 = blockIdx.x * 128;
    const unsigned short* Ab = A + b * sA;
    const unsigned short* Bb = B + b * sB;

    __shared__ __align__(16) unsigned short As[64 * 32];   // [m][k]
    __shared__ __align__(16) unsigned short Bs[128 * 32];  // [n][k]

    const int t    = threadIdx.x;
    const int lane = t & 63;
    const int w    = t >> 6;
    const int wm   = w >> 1, wn = w & 1;       // wave tile: 32 x 64

    f32x4 acc[2][4] = {};

    const int ar = t >> 2;
    const int ac = (t & 3) * 8;

    unsigned short* AsW  = As + w * 512;
    unsigned short* BsW0 = Bs + w * 512;
    unsigned short* BsW1 = Bs + 2048 + w * 512;
    const unsigned short* ga  = Ab + (long)(m0 + ar) * 1024 + ac;
    const unsigned short* gb0 = Bb + (long)(n0 + ar) * 1024 + ac;
    const unsigned short* gb1 = Bb + (long)(n0 + 64 + ar) * 1024 + ac;

    for (int k0 = 0; k0 < 1024; k0 += 32) {
        __syncthreads();
        gload_lds16(ga  + k0, AsW);
        gload_lds16(gb0 + k0, BsW0);
        gload_lds16(gb1 + k0, BsW1);
        __syncthreads();

        const int krow = (lane >> 4) * 8;
        bf16x8 af[2], bf[4];
#pragma unroll
        for (int fi = 0; fi < 2; ++fi)
            af[fi] = *(const bf16x8*)&As[(wm * 32 + fi * 16 + (lane & 15)) * 32 + krow];
#pragma unroll
        for (int fj = 0; fj < 4; ++fj)
            bf[fj] = *(const bf16x8*)&Bs[(wn * 64 + fj * 16 + (lane & 15)) * 32 + krow];
#pragma unroll
        for (int fi = 0; fi < 2; ++fi)
#pragma unroll
            for (int fj = 0; fj < 4; ++fj)
                acc[fi][fj] = __builtin_amdgcn_mfma_f32_16x16x32_bf16(
                    af[fi], bf[fj], acc[fi][fj], 0, 0, 0);
    }

    const int rbase = (lane >> 4) * 4;
    const int cn    = n0 + wn * 64 + (lane & 15);
#pragma unroll
    for (int fi = 0; fi < 2; ++fi) {
        const int mb = m0 + wm * 32 + fi * 16 + rbase;
#pragma unroll
        for (int r = 0; r < 4; ++r) {
            const int m = mb + r;
            if (m < M) {
#pragma unroll
                for (int fj = 0; fj < 4; ++fj)
                    C[b * sC + (long)m * 1024 + cn + fj * 16] = f2bf(acc[fi][fj][r]);
            }
        }
    }
}

// ---------------- sv_k: blocks [0,512) = scores GEMM (on-the-fly B convert);
// blocks [512,8704) = v_bfT transpose-convert. Independent roles, one launch.
__global__ __launch_bounds__(256) void sv_k(
    const unsigned short* __restrict__ A, const float* __restrict__ vf,
    float* __restrict__ C, unsigned short* __restrict__ vbfT, int M)
{
    __shared__ __align__(16) unsigned short sm_u[6144];   // 12 KB overlay
    const int bid = blockIdx.x;
    const int t = threadIdx.x;

    if (bid < 512) {
        // ---- scores: x = bid&7 (n-tile), y = (bid>>3)&1 (m-tile), b = bid>>4
        const int b  = bid >> 4;
        const int m0 = ((bid >> 3) & 1) * 64;
        const int n0 = (bid & 7) * 128;
        const unsigned short* Ab = A + (long)b * 131072;
        const float* Bb = vf + (long)b * 4194304;
        float* Cb = C + (long)b * 122880;

        unsigned short* As = sm_u;            // 2048 ushorts
        unsigned short* Bs = sm_u + 2048;     // 4096 ushorts

        const int lane = t & 63;
        const int w    = t >> 6;
        const int wm   = w >> 1, wn = w & 1;

        f32x4 acc[2][4] = {};

        const int ar = t >> 2;
        const int ac = (t & 3) * 8;

        unsigned short* AsW = As + w * 512;
        const unsigned short* ga = Ab + (long)(m0 + ar) * 1024 + ac;
        const float* gb0 = Bb + (long)(n0 + ar) * 1024 + ac;
        const float* gb1 = Bb + (long)(n0 + 64 + ar) * 1024 + ac;

        for (int k0 = 0; k0 < 1024; k0 += 32) {
            float4 v0a = *(const float4*)(gb0 + k0);
            float4 v0b = *(const float4*)(gb0 + k0 + 4);
            float4 v1a = *(const float4*)(gb1 + k0);
            float4 v1b = *(const float4*)(gb1 + k0 + 4);
            __syncthreads();
            gload_lds16(ga + k0, AsW);
            ushort4 o;
            o.x = f2bf(v0a.x); o.y = f2bf(v0a.y); o.z = f2bf(v0a.z); o.w = f2bf(v0a.w);
            *(ushort4*)&Bs[t * 8] = o;
            o.x = f2bf(v0b.x); o.y = f2bf(v0b.y); o.z = f2bf(v0b.z); o.w = f2bf(v0b.w);
            *(ushort4*)&Bs[t * 8 + 4] = o;
            o.x = f2bf(v1a.x); o.y = f2bf(v1a.y); o.z = f2bf(v1a.z); o.w = f2bf(v1a.w);
            *(ushort4*)&Bs[2048 + t * 8] = o;
            o.x = f2bf(v1b.x); o.y = f2bf(v1b.y); o.z = f2bf(v1b.z); o.w = f2bf(v1b.w);
            *(ushort4*)&Bs[2048 + t * 8 + 4] = o;
            __syncthreads();

            const int krow = (lane >> 4) * 8;
            bf16x8 af[2], bf[4];
#pragma unroll
            for (int fi = 0; fi < 2; ++fi)
                af[fi] = *(const bf16x8*)&As[(wm * 32 + fi * 16 + (lane & 15)) * 32 + krow];
#pragma unroll
            for (int fj = 0; fj < 4; ++fj)
                bf[fj] = *(const bf16x8*)&Bs[(wn * 64 + fj * 16 + (lane & 15)) * 32 + krow];
#pragma unroll
            for (int fi = 0; fi < 2; ++fi)
#pragma unroll
                for (int fj = 0; fj < 4; ++fj)
                    acc[fi][fj] = __builtin_amdgcn_mfma_f32_16x16x32_bf16(
                        af[fi], bf[fj], acc[fi][fj], 0, 0, 0);
        }

        const int rbase = (lane >> 4) * 4;
        const int cn    = n0 + wn * 64 + (lane & 15);
#pragma unroll
        for (int fi = 0; fi < 2; ++fi) {
            const int mb = m0 + wm * 32 + fi * 16 + rbase;
#pragma unroll
            for (int r = 0; r < 4; ++r) {
                const int m = mb + r;
                if (m < M) {
#pragma unroll
                    for (int fj = 0; fj < 4; ++fj)
                        Cb[(long)m * 1024 + cn + fj * 16] = acc[fi][fj][r];
                }
            }
        }
    } else {
        // ---- cvtT: tl = bid-512; b = tl>>8; e0 = (tl&15)*64; l0 = ((tl>>4)&15)*64
        const int tl = bid - 512;
        const int b  = tl >> 8;
        const int e0 = (tl & 15) * 64;
        const int l0 = ((tl >> 4) & 15) * 64;
        const float* src = vf + (long)b * 4194304;
        unsigned short* tile = sm_u;          // [64][72]
        const int r0 = t >> 4, c0 = (t & 15) * 4;
#pragma unroll
        for (int rr = 0; rr < 4; ++rr) {
            const int r = r0 + rr * 16;
            float4 v = *(const float4*)&src[(long)(l0 + r) * 1024 + e0 + c0];
            tile[r * 72 + c0 + 0] = f2bf(v.x); tile[r * 72 + c0 + 1] = f2bf(v.y);
            tile[r * 72 + c0 + 2] = f2bf(v.z); tile[r * 72 + c0 + 3] = f2bf(v.w);
        }
        __syncthreads();
#pragma unroll
        for (int rr = 0; rr < 4; ++rr) {
            const int idx = rr * 256 + t;
            const int e   = idx >> 4;
            const int c4  = (idx & 15) * 4;
            ushort4 o;
            o.x = tile[(c4 + 0) * 72 + e]; o.y = tile[(c4 + 1) * 72 + e];
            o.z = tile[(c4 + 2) * 72 + e]; o.w = tile[(c4 + 3) * 72 + e];
            *(ushort4*)&vbfT[(long)b * 1048576 + (long)(e0 + e) * 1024 + l0 + c4] = o;
        }
    }
}

// ---------------- projection bf16 MFMA GEMM (64x64 tile, gload_lds staging)
template <int OM>   // 0 = f32 only, 1 = dual, 2 = bf16 only
__global__ __launch_bounds__(256) void pgemm_k(
    const unsigned short* __restrict__ A, const unsigned short* __restrict__ B,
    const float* __restrict__ bias, float* __restrict__ C,
    unsigned short* __restrict__ Cbf,
    int M, int K, int lda, int ldb, int ldc)
{
    const int m0 = blockIdx.y * 64;
    const int n0 = blockIdx.x * 64;

    __shared__ __align__(16) unsigned short As[64 * 32];
    __shared__ __align__(16) unsigned short Bs[64 * 32];

    const int t    = threadIdx.x;
    const int lane = t & 63;
    const int w    = t >> 6;
    const int wm   = w >> 1, wn = w & 1;
    const int lm   = lane & 15, lg = lane >> 4;

    const int ar = t >> 2;
    const int ac = (t & 3) * 8;

    f32x4 acc[2][2] = {};

    unsigned short* AsW = As + w * 512;
    unsigned short* BsW = Bs + w * 512;
    const unsigned short* ga = A + (long)(m0 + ar) * lda + ac;
    const unsigned short* gb = B + (long)(n0 + ar) * ldb + ac;

    for (int k0 = 0; k0 < K; k0 += 32) {
        __syncthreads();
        gload_lds16(ga + k0, AsW);
        gload_lds16(gb + k0, BsW);
        __syncthreads();

        const int krow = lg * 8 & 24;
        bf16x8 af[2], bf[2];
#pragma unroll
        for (int fi = 0; fi < 2; ++fi)
            af[fi] = *(const bf16x8*)&As[(wm * 32 + fi * 16 + lm) * 32 + krow];
#pragma unroll
        for (int fj = 0; fj < 2; ++fj)
            bf[fj] = *(const bf16x8*)&Bs[(wn * 32 + fj * 16 + lm) * 32 + krow];
#pragma unroll
        for (int fi = 0; fi < 2; ++fi)
#pragma unroll
            for (int fj = 0; fj < 2; ++fj)
                acc[fi][fj] = __builtin_amdgcn_mfma_f32_16x16x32_bf16(
                    af[fi], bf[fj], acc[fi][fj], 0, 0, 0);
    }

    const int rbase = lg * 4;
#pragma unroll
    for (int fi = 0; fi < 2; ++fi) {
        const int mb = m0 + wm * 32 + fi * 16 + rbase;
#pragma unroll
        for (int r = 0; r < 4; ++r) {
            const int m = mb + r;
            if (m < M) {
#pragma unroll
                for (int fj = 0; fj < 2; ++fj) {
                    const int n = n0 + wn * 32 + fj * 16 + lm;
                    float v = acc[fi][fj][r];
                    if (bias) v += bias[n];
                    if constexpr (OM != 2) C[(long)m * ldc + n] = v;
                    if constexpr (OM >= 1) Cbf[(long)m * ldc + n] = f2bf(v);
                }
            }
        }
    }
}

// ---------------- qW kernel (unchanged)
__global__ __launch_bounds__(256) void qw_k(
    const unsigned short* __restrict__ qbf, const unsigned short* __restrict__ WkT,
    unsigned short* __restrict__ qW, float scale)
{
    const int z = blockIdx.y;
    const int b = z >> 3, h = z & 7;
    const int w = threadIdx.x >> 6, lane = threadIdx.x & 63;
    const int lm = lane & 15, lg = lane >> 4;
    const int n0w = blockIdx.x * 256 + w * 64;

    const unsigned short* Ar = qbf + (long)(b * 15 + lm) * 1024 + h * 128 + lg * 8;
    const unsigned short* Br = WkT + (long)(n0w + lm) * 1024 + h * 128 + lg * 8;

    bf16x8 af[4];
#pragma unroll
    for (int ks = 0; ks < 4; ++ks) af[ks] = *(const bf16x8*)(Ar + ks * 32);

    f32x4 acc[4] = {};
#pragma unroll
    for (int fj = 0; fj < 4; ++fj) {
#pragma unroll
        for (int ks = 0; ks < 4; ++ks) {
            bf16x8 bf = *(const bf16x8*)(Br + (long)fj * 16 * 1024 + ks * 32);
            acc[fj] = __builtin_amdgcn_mfma_f32_16x16x32_bf16(af[ks], bf, acc[fj], 0, 0, 0);
        }
    }

#pragma unroll
    for (int r = 0; r < 4; ++r) {
        const int m = lg * 4 + r;
        if (m < 15) {
#pragma unroll
            for (int fj = 0; fj < 4; ++fj)
                qW[(long)b * 131072 + (long)(m * 8 + h) * 1024 + n0w + fj * 16 + lm]
                    = f2bf(acc[fj][r] * scale);
        }
    }
}

// ---------------- ctx kernel (unchanged)
__global__ __launch_bounds__(256) void ctx_k(
    const unsigned short* __restrict__ cf, const unsigned short* __restrict__ Wvb,
    const float* __restrict__ bv, unsigned short* __restrict__ ctx)
{
    const int z = blockIdx.x;
    const int b = z >> 3, h = z & 7;
    const int w = threadIdx.x >> 6, lane = threadIdx.x & 63;
    const int lm = lane & 15, lg = lane >> 4;

    const unsigned short* Ar = cf + (long)b * 122880 + (long)(lm * 8 + h) * 1024 + lg * 8;
    const unsigned short* Br = Wvb + (long)(h * 128 + w * 32 + lm) * 1024 + lg * 8;

    f32x4 acc[2] = {};
    for (int k0 = 0; k0 < 1024; k0 += 32) {
        bf16x8 af = *(const bf16x8*)(Ar + k0);
        bf16x8 b0 = *(const bf16x8*)(Br + k0);
        bf16x8 b1 = *(const bf16x8*)(Br + 16 * 1024 + k0);
        acc[0] = __builtin_amdgcn_mfma_f32_16x16x32_bf16(af, b0, acc[0], 0, 0, 0);
        acc[1] = __builtin_amdgcn_mfma_f32_16x16x32_bf16(af, b1, acc[1], 0, 0, 0);
    }

#pragma unroll
    for (int r = 0; r < 4; ++r) {
        const int m = lg * 4 + r;
        if (m < 15) {
#pragma unroll
            for (int fj = 0; fj < 2; ++fj) {
                const int gcol = h * 128 + w * 32 + fj * 16 + lm;
                ctx[(long)(b * 15 + m) * 1024 + gcol] = f2bf(acc[fj][r] + bv[gcol]);
            }
        }
    }
}

// ---------------- uber conversion kernel (unchanged)
__global__ __launch_bounds__(256) void uber_cvt_k(
    const int* __restrict__ nodes, const float* __restrict__ bboxes,
    const float* __restrict__ emb, const float* __restrict__ Wb,
    const float* __restrict__ bb, unsigned short* __restrict__ qbf,
    const float* __restrict__ Wq, const float* __restrict__ Wo,
    const float* __restrict__ Wv, const float* __restrict__ W1,
    const float* __restrict__ Wk,
    unsigned short* __restrict__ dWq, unsigned short* __restrict__ dWo,
    unsigned short* __restrict__ dWv, unsigned short* __restrict__ dW1r,
    unsigned short* __restrict__ dWkT)
{
    __shared__ unsigned short tile[64][72];
    const int bid = blockIdx.x;
    const int t = threadIdx.x;

    if (bid < 4096) {
        const int which = bid >> 10;
        const int i = (bid & 1023) * 256 + t;
        const float* s;
        unsigned short* d;
        if (which == 3) {
            const int flat = i * 4, n = flat >> 10, k = flat & 1023;
            s = (n < 512) ? W1 + (long)n * 2048 + k
                          : W1 + (long)(n - 512) * 2048 + 1024 + k;
            d = dW1r + flat;
        } else {
            s = (which == 0 ? Wq : which == 1 ? Wo : Wv) + (long)i * 4;
            d = (which == 0 ? dWq : which == 1 ? dWo : dWv) + (long)i * 4;
        }
        float4 v = *(const float4*)s;
        ushort4 o;
        o.x = f2bf(v.x); o.y = f2bf(v.y); o.z = f2bf(v.z); o.w = f2bf(v.w);
        *(ushort4*)d = o;
    } else if (bid < 4352) {
        const int tl = bid - 4096;
        const int d0 = (tl >> 4) * 64, e0 = (tl & 15) * 64;
        const int r0 = t >> 4, c0 = (t & 15) * 4;
#pragma unroll
        for (int rr = 0; rr < 4; ++rr) {
            const int r = r0 + rr * 16;
            float4 v = *(const float4*)&Wk[(long)(d0 + r) * 1024 + e0 + c0];
            tile[r][c0 + 0] = f2bf(v.x); tile[r][c0 + 1] = f2bf(v.y);
            tile[r][c0 + 2] = f2bf(v.z); tile[r][c0 + 3] = f2bf(v.w);
        }
        __syncthreads();
#pragma unroll
        for (int rr = 0; rr < 4; ++rr) {
            const int idx = rr * 256 + t;
            const int e = idx >> 4, c4 = (idx & 15) * 4;
            ushort4 o;
            o.x = tile[c4 + 0][e]; o.y = tile[c4 + 1][e];
            o.z = tile[c4 + 2][e]; o.w = tile[c4 + 3][e];
            *(ushort4*)&dWkT[(long)(e0 + e) * 1024 + d0 + c4] = o;
        }
    } else {
        const int blk = bid - 4352;
        const int node = nodes[blk];
        const int idx = node < 0 ? 0 : node;
        const float4 bx = *(const float4*)&bboxes[blk * 4];
        const float* er = emb + (long)idx * 1024;
        for (int d = t; d < 1024; d += 256) {
            const float4 w = *(const float4*)&Wb[d * 4];
            qbf[(long)blk * 1024 + d] = f2bf(
                er[d] + bb[d] + bx.x * w.x + bx.y * w.y + bx.z * w.z + bx.w * w.w);
        }
    }
}

// ---------------- row softmax over 1024; fp32 in, bf16 out (padded 128 rows/b)
__global__ __launch_bounds__(256) void softmax_k(
    const float* __restrict__ sc, unsigned short* __restrict__ attn)
{
    __shared__ float red[4];
    const int blk = blockIdx.x;              // b*120 + r
    const int b = blk / 120, r = blk % 120;
    const float* p = sc + (long)blk * 1024;
    const int t = threadIdx.x;
    float4 v = *(const float4*)&p[t * 4];

    float m = fmaxf(fmaxf(v.x, v.y), fmaxf(v.z, v.w));
#pragma unroll
    for (int o = 32; o; o >>= 1) m = fmaxf(m, __shfl_xor(m, o));
    if ((t & 63) == 0) red[t >> 6] = m;
    __syncthreads();
    m = fmaxf(fmaxf(red[0], red[1]), fmaxf(red[2], red[3]));
    __syncthreads();

    v.x = __expf(v.x - m); v.y = __expf(v.y - m);
    v.z = __expf(v.z - m); v.w = __expf(v.w - m);
    float s = v.x + v.y + v.z + v.w;
#pragma unroll
    for (int o = 32; o; o >>= 1) s += __shfl_xor(s, o);
    if ((t & 63) == 0) red[t >> 6] = s;
    __syncthreads();
    s = red[0] + red[1] + red[2] + red[3];
    const float inv = 1.0f / s;
    ushort4 o;
    o.x = f2bf(v.x * inv); o.y = f2bf(v.y * inv);
    o.z = f2bf(v.z * inv); o.w = f2bf(v.w * inv);
    *(ushort4*)&attn[(long)(b * 128 + r) * 1024 + t * 4] = o;
}

// ---------------- tail kernel: blocks [0,480) = edge; [480,512) = full energy/b
__global__ __launch_bounds__(320) void tail_k(
    const float* __restrict__ hh, const float* __restrict__ b1,
    const float* __restrict__ W2, const float* __restrict__ b2,
    const float* __restrict__ enr, const int* __restrict__ nodes,
    const float* __restrict__ Wh1, const float* __restrict__ bh1,
    const float* __restrict__ Wh2, const float* __restrict__ bh2,
    float* __restrict__ out)
{
    __shared__ float sm[8993];   // edge: hiS|b1S|hjS|w2S; energy: gf[1024]|hid[256]|red[4]
    const int bid = blockIdx.x;
    const int t = threadIdx.x;

    if (bid < 480) {             // ---- edge: b = bid/15, i = bid%15
        const int b = bid / 15, i = bid % 15;
        float* hiS = sm;
        float* b1S = sm + 256;
        float* hjS = sm + 512;           // [15][257]
        float* w2S = sm + 512 + 3855;    // [18][257]
        const int j = t / 18, c = t % 18;
        float acc = 0.0f;

        for (int u0 = 0; u0 < 512; u0 += 256) {
            __syncthreads();
            if (t < 64) {
                float4 v = *(const float4*)&hh[(long)(b * 15 + i) * 1024 + u0 + t * 4];
                hiS[t * 4 + 0] = v.x; hiS[t * 4 + 1] = v.y;
                hiS[t * 4 + 2] = v.z; hiS[t * 4 + 3] = v.w;
            } else if (t < 128) {
                const int tt = t - 64;
                float4 v = *(const float4*)&b1[u0 + tt * 4];
                b1S[tt * 4 + 0] = v.x; b1S[tt * 4 + 1] = v.y;
                b1S[tt * 4 + 2] = v.z; b1S[tt * 4 + 3] = v.w;
            }
            for (int x = t; x < 960; x += 320) {
                const int r = x >> 6, cc = (x & 63) * 4;
                float4 v = *(const float4*)&hh[(long)(b * 15 + r) * 1024 + 512 + u0 + cc];
                hjS[r * 257 + cc + 0] = v.x; hjS[r * 257 + cc + 1] = v.y;
                hjS[r * 257 + cc + 2] = v.z; hjS[r * 257 + cc + 3] = v.w;
            }
            for (int x = t; x < 1152; x += 320) {
                const int r = x >> 6, cc = (x & 63) * 4;
                float4 v = *(const float4*)&W2[(long)r * 512 + u0 + cc];
                w2S[r * 257 + cc + 0] = v.x; w2S[r * 257 + cc + 1] = v.y;
                w2S[r * 257 + cc + 2] = v.z; w2S[r * 257 + cc + 3] = v.w;
            }
            __syncthreads();
            if (t < 270) {
                for (int u = 0; u < 256; ++u) {
                    float p = hiS[u] + hjS[j * 257 + u] + b1S[u];
                    p = p > 0.0f ? p : 0.0f;
                    acc += p * w2S[c * 257 + u];
                }
            }
        }
        if (t < 270)
            out[((long)(bid) * 15 + j) * 18 + c] = acc + b2[c];
    } else {                     // ---- energy: one block per b, all 256 units
        const int b = bid - 480;
        float* gf  = sm;          // [1024]
        float* hid = sm + 1024;   // [256]
        float* red = sm + 1280;   // [4]

        int cnt = 0;
#pragma unroll
        for (int n = 0; n < 15; ++n) cnt += (nodes[b * 15 + n] != -1) ? 1 : 0;
        const float inv_valid = 1.0f / fmaxf((float)cnt, 1.0f);
        if (t < 256) {
            for (int e = t; e < 1024; e += 256) {
                float s = 0.0f;
#pragma unroll
                for (int n = 0; n < 15; ++n) {
                    const bool ok = nodes[b * 15 + n] != -1;
                    s += ok ? enr[(long)(b * 15 + n) * 1024 + e] : 0.0f;
                }
                gf[e] = s * inv_valid;
            }
        }
        __syncthreads();
        if (t < 256) {
            const int wave = t >> 6, lane = t & 63;
            for (int c16 = 0; c16 < 256; c16 += 16) {
#pragma unroll
                for (int r = 0; r < 4; ++r) {
                    const int u = c16 + wave * 4 + r;
                    float s = 0.0f;
#pragma unroll
                    for (int e0 = 0; e0 < 1024; e0 += 64)
                        s += gf[e0 + lane] * Wh1[(long)u * 1024 + e0 + lane];
#pragma unroll
                    for (int o = 32; o; o >>= 1) s += __shfl_xor(s, o);
                    if (lane == 0)
                        hid[u] = fmaxf(s + bh1[u], 0.0f) * Wh2[u];
                }
            }
        }
        __syncthreads();
        if (t < 256) {
            float v = hid[t];
#pragma unroll
            for (int o = 32; o; o >>= 1) v += __shfl_xor(v, o);
            if ((t & 63) == 0) red[t >> 6] = v;
        }
        __syncthreads();
        if (t == 0) out[129600 + b] = red[0] + red[1] + red[2] + red[3] + bh2[0];
    }
}

// ---------------------------------------------------------------------------
extern "C" void kernel_launch(void* const* d_in, const int* in_sizes, int n_in,
                              void* d_out, int out_size, void* d_ws, size_t ws_size,
                              hipStream_t stream)
{
    const float* visual = (const float*)d_in[0];
    const int*   nodes  = (const int*)  d_in[1];
    const float* bboxes = (const float*)d_in[2];
    const float* emb    = (const float*)d_in[3];
    const float* Wb     = (const float*)d_in[4];
    const float* bb     = (const float*)d_in[5];
    const float* Wq     = (const float*)d_in[6];
    const float* bq     = (const float*)d_in[7];
    const float* Wk     = (const float*)d_in[8];
    /* bk (d_in[9]) cancels in softmax */
    const float* Wv     = (const float*)d_in[10];
    const float* bv     = (const float*)d_in[11];
    const float* Wo     = (const float*)d_in[12];
    const float* bo     = (const float*)d_in[13];
    const float* W1     = (const float*)d_in[14];
    const float* b1     = (const float*)d_in[15];
    const float* W2     = (const float*)d_in[16];
    const float* b2     = (const float*)d_in[17];
    const float* Wh1    = (const float*)d_in[18];
    const float* bh1    = (const float*)d_in[19];
    const float* Wh2    = (const float*)d_in[20];
    const float* bh2    = (const float*)d_in[21];

    float* out = (float*)d_out;
    float* ws  = (float*)d_ws;

    // workspace layout (offsets in fp32 words)
    unsigned short* query_bf = (unsigned short*)(ws);            // 512x1024 bf16
    unsigned short* q_bf     = (unsigned short*)(ws + 131072);   // 512x1024 bf16
    float* scores = ws + 262144;              // 32*120*1024 f32
    unsigned short* ctxf_bf  = (unsigned short*)(ws + 4194304);  // 32*120*1024 bf16
    unsigned short* ctx_bf   = (unsigned short*)(ws + 6160384);  // 512x1024 bf16
    float* enr    = ws + 6422528;             // 480*1024 f32
    unsigned short* enr_bf   = (unsigned short*)(ws + 6914048);  // 512x1024 bf16
    float* hh     = ws + 7176192;             // 480*1024 f32 (hi|hj)
    unsigned short* Wq_bf  = (unsigned short*)(ws + 7667712);    // 1024x1024 bf16
    unsigned short* Wo_bf  = (unsigned short*)(ws + 8192000);    // 1024x1024 bf16
    unsigned short* Wv_bf  = (unsigned short*)(ws + 8716288);    // 1024x1024 bf16
    unsigned short* W1r_bf = (unsigned short*)(ws + 9240576);    // 1024x1024 bf16
    unsigned short* WkT_bf = (unsigned short*)(ws + 9764864);    // 1024x1024 bf16
    unsigned short* qW_bf   = (unsigned short*)(ws + 10289152);  // 32*128*1024 bf16
    unsigned short* attn_bf = (unsigned short*)(ws + 12386304);  // 32*128*1024 bf16
    unsigned short* v_bfT   = (unsigned short*)(ws + 31260672);  // 32*1024*1024 bf16

    const float inv_sqrt_hd = 0.08838834764831845f;  // 1/sqrt(128)
    const float* v_f = visual + 3 * 1048576;         // frame T-1; batch stride 4*1048576

    // 1) weight/query conversions
    uber_cvt_k<<<4832, 256, 0, stream>>>(
        nodes, bboxes, emb, Wb, bb, query_bf,
        Wq, Wo, Wv, W1, Wk, Wq_bf, Wo_bf, Wv_bf, W1r_bf, WkT_bf);

    // 2) q_bf = query_bf @ Wq_bf^T + bq   (MFMA, bf16-only out)
    pgemm_k<2><<<dim3(16, 8), 256, 0, stream>>>(
        query_bf, Wq_bf, bq, nullptr, q_bf, 480, 1024, 1024, 1024, 1024);

    // 3) qW_bf = (q_bf @ WkT_bf^T) * inv_sqrt_hd   (MFMA, batch (b,h))
    qw_k<<<dim3(4, 256), 256, 0, stream>>>(q_bf, WkT_bf, qW_bf, inv_sqrt_hd);

    // 4) scores (on-the-fly v convert) + v_bfT transpose, fused & concurrent
    sv_k<<<8704, 256, 0, stream>>>(qW_bf, v_f, scores, v_bfT, 120);

    // 5) softmax over l -> bf16 attn
    softmax_k<<<3840, 256, 0, stream>>>(scores, attn_bf);

    // 6) ctxf_bf[b] = attn[b] @ v_bfT[b]^T  (MFMA, bf16 out)
    bfgemm_k<<<dim3(8, 2, 32), 256, 0, stream>>>(
        attn_bf, v_bfT, ctxf_bf, 120, 131072, 1048576, 122880);

    // 7) ctx_bf = ctxf_bf @ Wv^T + bv      (MFMA, batch (b,h))
    ctx_k<<<256, 256, 0, stream>>>(ctxf_bf, Wv_bf, bv, ctx_bf);

    // 8) enr = ctx_bf @ Wo_bf^T + bo       (MFMA, dual out)
    pgemm_k<1><<<dim3(16, 8), 256, 0, stream>>>(
        ctx_bf, Wo_bf, bo, enr, enr_bf, 480, 1024, 1024, 1024, 1024);

    // 9) hh = enr_bf @ W1r_bf^T            (MFMA; cols 0..511 hi, 512..1023 hj)
    pgemm_k<0><<<dim3(16, 8), 256, 0, stream>>>(
        enr_bf, W1r_bf, nullptr, hh, nullptr, 480, 1024, 1024, 1024, 1024);

    // 10) edge + full energy fused -> out
    tail_k<<<512, 320, 0, stream>>>(
        hh, b1, W2, b2, enr, nodes, Wh1, bh1, Wh2, bh2, out);
}

// Round 15
// 216.921 us; speedup vs baseline: 1.1093x; 1.1093x over previous
//
#include <hip/hip_runtime.h>

// ---------------------------------------------------------------------------
// RelationalTransformer: B=32 T=4 L=1024 D=1024 H=8 Hd=128 N=15
// out = edge_logits (32*15*15*18 = 129600) ++ energy (32)   [fp32]
//
// R15 = exact revert to R13 (measured best: 214.9us). R14's two fusions
// (sv_k, 32-block energy) both regressed (+26us) and are dropped.
// ---------------------------------------------------------------------------

typedef __attribute__((ext_vector_type(8))) short bf16x8;   // 8 bf16 in 4 VGPRs
typedef __attribute__((ext_vector_type(4))) float f32x4;

__device__ __forceinline__ unsigned short f2bf(float f) {   // RNE float->bf16
    unsigned int u = __float_as_uint(f);
    u = u + 0x7FFFu + ((u >> 16) & 1u);
    return (unsigned short)(u >> 16);
}

// async global->LDS, 16B per lane, dest = wave-uniform base + lane*16
__device__ __forceinline__ void gload_lds16(const void* g, void* l) {
    __builtin_amdgcn_global_load_lds(
        (const __attribute__((address_space(1))) void*)g,
        (__attribute__((address_space(3))) void*)l,
        16, 0, 0);
}

// ---------------- PV bf16 MFMA GEMM (64x128 tile, 4 waves): C = A @ B^T
__global__ __launch_bounds__(256) void bfgemm_k(
    const unsigned short* __restrict__ A, const unsigned short* __restrict__ B,
    unsigned short* __restrict__ C, int M, long sA, long sB, long sC)
{
    const int b  = blockIdx.z;
    const int m0 = blockIdx.y * 64;
    const int n0 = blockIdx.x * 128;
    const unsigned short* Ab = A + b * sA;
    const unsigned short* Bb = B + b * sB;

    __shared__ __align__(16) unsigned short As[64 * 32];   // [m][k]
    __shared__ __align__(16) unsigned short Bs[128 * 32];  // [n][k]

    const int t    = threadIdx.x;
    const int lane = t & 63;
    const int w    = t >> 6;
    const int wm   = w >> 1, wn = w & 1;       // wave tile: 32 x 64

    f32x4 acc[2][4] = {};

    const int ar = t >> 2;              // staging row (0..63)
    const int ac = (t & 3) * 8;         // staging k-offset (bf16 elems)

    unsigned short* AsW  = As + w * 512;
    unsigned short* BsW0 = Bs + w * 512;
    unsigned short* BsW1 = Bs + 2048 + w * 512;
    const unsigned short* ga  = Ab + (long)(m0 + ar) * 1024 + ac;
    const unsigned short* gb0 = Bb + (long)(n0 + ar) * 1024 + ac;
    const unsigned short* gb1 = Bb + (long)(n0 + 64 + ar) * 1024 + ac;

    for (int k0 = 0; k0 < 1024; k0 += 32) {
        __syncthreads();
        gload_lds16(ga  + k0, AsW);
        gload_lds16(gb0 + k0, BsW0);
        gload_lds16(gb1 + k0, BsW1);
        __syncthreads();

        const int krow = (lane >> 4) * 8;
        bf16x8 af[2], bf[4];
#pragma unroll
        for (int fi = 0; fi < 2; ++fi)
            af[fi] = *(const bf16x8*)&As[(wm * 32 + fi * 16 + (lane & 15)) * 32 + krow];
#pragma unroll
        for (int fj = 0; fj < 4; ++fj)
            bf[fj] = *(const bf16x8*)&Bs[(wn * 64 + fj * 16 + (lane & 15)) * 32 + krow];
#pragma unroll
        for (int fi = 0; fi < 2; ++fi)
#pragma unroll
            for (int fj = 0; fj < 4; ++fj)
                acc[fi][fj] = __builtin_amdgcn_mfma_f32_16x16x32_bf16(
                    af[fi], bf[fj], acc[fi][fj], 0, 0, 0);
    }

    const int rbase = (lane >> 4) * 4;
    const int cn    = n0 + wn * 64 + (lane & 15);
#pragma unroll
    for (int fi = 0; fi < 2; ++fi) {
        const int mb = m0 + wm * 32 + fi * 16 + rbase;
#pragma unroll
        for (int r = 0; r < 4; ++r) {
            const int m = mb + r;
            if (m < M) {
#pragma unroll
                for (int fj = 0; fj < 4; ++fj)
                    C[b * sC + (long)m * 1024 + cn + fj * 16] = f2bf(acc[fi][fj][r]);
            }
        }
    }
}

// ---------------- scores GEMM: A bf16 (gload), B = v_f fp32 converted on the
// fly (reg-stage + RNE cvt -> LDS bytes identical to reading v_bf).
__global__ __launch_bounds__(256) void sgemm_k(
    const unsigned short* __restrict__ A, const float* __restrict__ Bf,
    float* __restrict__ C, int M, long sA, long sB, long sC)
{
    const int b  = blockIdx.z;
    const int m0 = blockIdx.y * 64;
    const int n0 = blockIdx.x * 128;
    const unsigned short* Ab = A + b * sA;
    const float* Bb = Bf + b * sB;
    float* Cb = C + b * sC;

    __shared__ __align__(16) unsigned short As[64 * 32];
    __shared__ __align__(16) unsigned short Bs[128 * 32];

    const int t    = threadIdx.x;
    const int lane = t & 63;
    const int w    = t >> 6;
    const int wm   = w >> 1, wn = w & 1;

    f32x4 acc[2][4] = {};

    const int ar = t >> 2;
    const int ac = (t & 3) * 8;

    unsigned short* AsW = As + w * 512;
    const unsigned short* ga = Ab + (long)(m0 + ar) * 1024 + ac;
    const float* gb0 = Bb + (long)(n0 + ar) * 1024 + ac;
    const float* gb1 = Bb + (long)(n0 + 64 + ar) * 1024 + ac;

    for (int k0 = 0; k0 < 1024; k0 += 32) {
        float4 v0a = *(const float4*)(gb0 + k0);
        float4 v0b = *(const float4*)(gb0 + k0 + 4);
        float4 v1a = *(const float4*)(gb1 + k0);
        float4 v1b = *(const float4*)(gb1 + k0 + 4);
        __syncthreads();                     // prior-iter ds_reads done
        gload_lds16(ga + k0, AsW);
        ushort4 o;
        o.x = f2bf(v0a.x); o.y = f2bf(v0a.y); o.z = f2bf(v0a.z); o.w = f2bf(v0a.w);
        *(ushort4*)&Bs[t * 8] = o;
        o.x = f2bf(v0b.x); o.y = f2bf(v0b.y); o.z = f2bf(v0b.z); o.w = f2bf(v0b.w);
        *(ushort4*)&Bs[t * 8 + 4] = o;
        o.x = f2bf(v1a.x); o.y = f2bf(v1a.y); o.z = f2bf(v1a.z); o.w = f2bf(v1a.w);
        *(ushort4*)&Bs[2048 + t * 8] = o;
        o.x = f2bf(v1b.x); o.y = f2bf(v1b.y); o.z = f2bf(v1b.z); o.w = f2bf(v1b.w);
        *(ushort4*)&Bs[2048 + t * 8 + 4] = o;
        __syncthreads();                     // drains vmcnt+lgkm

        const int krow = (lane >> 4) * 8;
        bf16x8 af[2], bf[4];
#pragma unroll
        for (int fi = 0; fi < 2; ++fi)
            af[fi] = *(const bf16x8*)&As[(wm * 32 + fi * 16 + (lane & 15)) * 32 + krow];
#pragma unroll
        for (int fj = 0; fj < 4; ++fj)
            bf[fj] = *(const bf16x8*)&Bs[(wn * 64 + fj * 16 + (lane & 15)) * 32 + krow];
#pragma unroll
        for (int fi = 0; fi < 2; ++fi)
#pragma unroll
            for (int fj = 0; fj < 4; ++fj)
                acc[fi][fj] = __builtin_amdgcn_mfma_f32_16x16x32_bf16(
                    af[fi], bf[fj], acc[fi][fj], 0, 0, 0);
    }

    const int rbase = (lane >> 4) * 4;
    const int cn    = n0 + wn * 64 + (lane & 15);
#pragma unroll
    for (int fi = 0; fi < 2; ++fi) {
        const int mb = m0 + wm * 32 + fi * 16 + rbase;
#pragma unroll
        for (int r = 0; r < 4; ++r) {
            const int m = mb + r;
            if (m < M) {
#pragma unroll
                for (int fj = 0; fj < 4; ++fj)
                    Cb[(long)m * 1024 + cn + fj * 16] = acc[fi][fj][r];
            }
        }
    }
}

// ---------------- projection bf16 MFMA GEMM (64x64 tile, gload_lds staging)
template <int OM>   // 0 = f32 only, 1 = dual, 2 = bf16 only
__global__ __launch_bounds__(256) void pgemm_k(
    const unsigned short* __restrict__ A, const unsigned short* __restrict__ B,
    const float* __restrict__ bias, float* __restrict__ C,
    unsigned short* __restrict__ Cbf,
    int M, int K, int lda, int ldb, int ldc)
{
    const int m0 = blockIdx.y * 64;
    const int n0 = blockIdx.x * 64;

    __shared__ __align__(16) unsigned short As[64 * 32];
    __shared__ __align__(16) unsigned short Bs[64 * 32];

    const int t    = threadIdx.x;
    const int lane = t & 63;
    const int w    = t >> 6;
    const int wm   = w >> 1, wn = w & 1;
    const int lm   = lane & 15, lg = lane >> 4;

    const int ar = t >> 2;
    const int ac = (t & 3) * 8;

    f32x4 acc[2][2] = {};

    unsigned short* AsW = As + w * 512;
    unsigned short* BsW = Bs + w * 512;
    const unsigned short* ga = A + (long)(m0 + ar) * lda + ac;
    const unsigned short* gb = B + (long)(n0 + ar) * ldb + ac;

    for (int k0 = 0; k0 < K; k0 += 32) {
        __syncthreads();
        gload_lds16(ga + k0, AsW);
        gload_lds16(gb + k0, BsW);
        __syncthreads();

        const int krow = lg * 8 & 24;
        bf16x8 af[2], bf[2];
#pragma unroll
        for (int fi = 0; fi < 2; ++fi)
            af[fi] = *(const bf16x8*)&As[(wm * 32 + fi * 16 + lm) * 32 + krow];
#pragma unroll
        for (int fj = 0; fj < 2; ++fj)
            bf[fj] = *(const bf16x8*)&Bs[(wn * 32 + fj * 16 + lm) * 32 + krow];
#pragma unroll
        for (int fi = 0; fi < 2; ++fi)
#pragma unroll
            for (int fj = 0; fj < 2; ++fj)
                acc[fi][fj] = __builtin_amdgcn_mfma_f32_16x16x32_bf16(
                    af[fi], bf[fj], acc[fi][fj], 0, 0, 0);
    }

    const int rbase = lg * 4;
#pragma unroll
    for (int fi = 0; fi < 2; ++fi) {
        const int mb = m0 + wm * 32 + fi * 16 + rbase;
#pragma unroll
        for (int r = 0; r < 4; ++r) {
            const int m = mb + r;
            if (m < M) {
#pragma unroll
                for (int fj = 0; fj < 2; ++fj) {
                    const int n = n0 + wn * 32 + fj * 16 + lm;
                    float v = acc[fi][fj][r];
                    if (bias) v += bias[n];
                    if constexpr (OM != 2) C[(long)m * ldc + n] = v;
                    if constexpr (OM >= 1) Cbf[(long)m * ldc + n] = f2bf(v);
                }
            }
        }
    }
}

// ---------------- qW kernel
__global__ __launch_bounds__(256) void qw_k(
    const unsigned short* __restrict__ qbf, const unsigned short* __restrict__ WkT,
    unsigned short* __restrict__ qW, float scale)
{
    const int z = blockIdx.y;
    const int b = z >> 3, h = z & 7;
    const int w = threadIdx.x >> 6, lane = threadIdx.x & 63;
    const int lm = lane & 15, lg = lane >> 4;
    const int n0w = blockIdx.x * 256 + w * 64;

    const unsigned short* Ar = qbf + (long)(b * 15 + lm) * 1024 + h * 128 + lg * 8;
    const unsigned short* Br = WkT + (long)(n0w + lm) * 1024 + h * 128 + lg * 8;

    bf16x8 af[4];
#pragma unroll
    for (int ks = 0; ks < 4; ++ks) af[ks] = *(const bf16x8*)(Ar + ks * 32);

    f32x4 acc[4] = {};
#pragma unroll
    for (int fj = 0; fj < 4; ++fj) {
#pragma unroll
        for (int ks = 0; ks < 4; ++ks) {
            bf16x8 bf = *(const bf16x8*)(Br + (long)fj * 16 * 1024 + ks * 32);
            acc[fj] = __builtin_amdgcn_mfma_f32_16x16x32_bf16(af[ks], bf, acc[fj], 0, 0, 0);
        }
    }

#pragma unroll
    for (int r = 0; r < 4; ++r) {
        const int m = lg * 4 + r;
        if (m < 15) {
#pragma unroll
            for (int fj = 0; fj < 4; ++fj)
                qW[(long)b * 131072 + (long)(m * 8 + h) * 1024 + n0w + fj * 16 + lm]
                    = f2bf(acc[fj][r] * scale);
        }
    }
}

// ---------------- ctx kernel
__global__ __launch_bounds__(256) void ctx_k(
    const unsigned short* __restrict__ cf, const unsigned short* __restrict__ Wvb,
    const float* __restrict__ bv, unsigned short* __restrict__ ctx)
{
    const int z = blockIdx.x;
    const int b = z >> 3, h = z & 7;
    const int w = threadIdx.x >> 6, lane = threadIdx.x & 63;
    const int lm = lane & 15, lg = lane >> 4;

    const unsigned short* Ar = cf + (long)b * 122880 + (long)(lm * 8 + h) * 1024 + lg * 8;
    const unsigned short* Br = Wvb + (long)(h * 128 + w * 32 + lm) * 1024 + lg * 8;

    f32x4 acc[2] = {};
    for (int k0 = 0; k0 < 1024; k0 += 32) {
        bf16x8 af = *(const bf16x8*)(Ar + k0);
        bf16x8 b0 = *(const bf16x8*)(Br + k0);
        bf16x8 b1 = *(const bf16x8*)(Br + 16 * 1024 + k0);
        acc[0] = __builtin_amdgcn_mfma_f32_16x16x32_bf16(af, b0, acc[0], 0, 0, 0);
        acc[1] = __builtin_amdgcn_mfma_f32_16x16x32_bf16(af, b1, acc[1], 0, 0, 0);
    }

#pragma unroll
    for (int r = 0; r < 4; ++r) {
        const int m = lg * 4 + r;
        if (m < 15) {
#pragma unroll
            for (int fj = 0; fj < 2; ++fj) {
                const int gcol = h * 128 + w * 32 + fj * 16 + lm;
                ctx[(long)(b * 15 + m) * 1024 + gcol] = f2bf(acc[fj][r] + bv[gcol]);
            }
        }
    }
}

// ---------------- uber conversion kernel
__global__ __launch_bounds__(256) void uber_cvt_k(
    const int* __restrict__ nodes, const float* __restrict__ bboxes,
    const float* __restrict__ emb, const float* __restrict__ Wb,
    const float* __restrict__ bb, unsigned short* __restrict__ qbf,
    const float* __restrict__ Wq, const float* __restrict__ Wo,
    const float* __restrict__ Wv, const float* __restrict__ W1,
    const float* __restrict__ Wk,
    unsigned short* __restrict__ dWq, unsigned short* __restrict__ dWo,
    unsigned short* __restrict__ dWv, unsigned short* __restrict__ dW1r,
    unsigned short* __restrict__ dWkT)
{
    __shared__ unsigned short tile[64][72];
    const int bid = blockIdx.x;
    const int t = threadIdx.x;

    if (bid < 4096) {
        const int which = bid >> 10;
        const int i = (bid & 1023) * 256 + t;
        const float* s;
        unsigned short* d;
        if (which == 3) {
            const int flat = i * 4, n = flat >> 10, k = flat & 1023;
            s = (n < 512) ? W1 + (long)n * 2048 + k
                          : W1 + (long)(n - 512) * 2048 + 1024 + k;
            d = dW1r + flat;
        } else {
            s = (which == 0 ? Wq : which == 1 ? Wo : Wv) + (long)i * 4;
            d = (which == 0 ? dWq : which == 1 ? dWo : dWv) + (long)i * 4;
        }
        float4 v = *(const float4*)s;
        ushort4 o;
        o.x = f2bf(v.x); o.y = f2bf(v.y); o.z = f2bf(v.z); o.w = f2bf(v.w);
        *(ushort4*)d = o;
    } else if (bid < 4352) {
        const int tl = bid - 4096;
        const int d0 = (tl >> 4) * 64, e0 = (tl & 15) * 64;
        const int r0 = t >> 4, c0 = (t & 15) * 4;
#pragma unroll
        for (int rr = 0; rr < 4; ++rr) {
            const int r = r0 + rr * 16;
            float4 v = *(const float4*)&Wk[(long)(d0 + r) * 1024 + e0 + c0];
            tile[r][c0 + 0] = f2bf(v.x); tile[r][c0 + 1] = f2bf(v.y);
            tile[r][c0 + 2] = f2bf(v.z); tile[r][c0 + 3] = f2bf(v.w);
        }
        __syncthreads();
#pragma unroll
        for (int rr = 0; rr < 4; ++rr) {
            const int idx = rr * 256 + t;
            const int e = idx >> 4, c4 = (idx & 15) * 4;
            ushort4 o;
            o.x = tile[c4 + 0][e]; o.y = tile[c4 + 1][e];
            o.z = tile[c4 + 2][e]; o.w = tile[c4 + 3][e];
            *(ushort4*)&dWkT[(long)(e0 + e) * 1024 + d0 + c4] = o;
        }
    } else {
        const int blk = bid - 4352;
        const int node = nodes[blk];
        const int idx = node < 0 ? 0 : node;
        const float4 bx = *(const float4*)&bboxes[blk * 4];
        const float* er = emb + (long)idx * 1024;
        for (int d = t; d < 1024; d += 256) {
            const float4 w = *(const float4*)&Wb[d * 4];
            qbf[(long)blk * 1024 + d] = f2bf(
                er[d] + bb[d] + bx.x * w.x + bx.y * w.y + bx.z * w.z + bx.w * w.w);
        }
    }
}

// ---------------- transpose-only convert: v_bfT[b][e][l] = bf16(v_f[b][l][e])
__global__ __launch_bounds__(256) void cvtT_k(
    const float* __restrict__ vf, unsigned short* __restrict__ vbfT)
{
    const int b  = blockIdx.z;
    const int e0 = blockIdx.x * 64;
    const int l0 = blockIdx.y * 64;
    const float* src = vf + (long)b * 4194304;   // batch stride = T*L*D
    __shared__ unsigned short tile[64][72];
    const int t = threadIdx.x;
    const int r0 = t >> 4, c0 = (t & 15) * 4;
#pragma unroll
    for (int rr = 0; rr < 4; ++rr) {
        const int r = r0 + rr * 16;
        float4 v = *(const float4*)&src[(long)(l0 + r) * 1024 + e0 + c0];
        tile[r][c0 + 0] = f2bf(v.x); tile[r][c0 + 1] = f2bf(v.y);
        tile[r][c0 + 2] = f2bf(v.z); tile[r][c0 + 3] = f2bf(v.w);
    }
    __syncthreads();
#pragma unroll
    for (int rr = 0; rr < 4; ++rr) {
        const int idx = rr * 256 + t;
        const int e   = idx >> 4;
        const int c4  = (idx & 15) * 4;
        ushort4 o;
        o.x = tile[c4 + 0][e]; o.y = tile[c4 + 1][e];
        o.z = tile[c4 + 2][e]; o.w = tile[c4 + 3][e];
        *(ushort4*)&vbfT[(long)b * 1048576 + (long)(e0 + e) * 1024 + l0 + c4] = o;
    }
}

// ---------------- row softmax over 1024; fp32 in, bf16 out (padded 128 rows/b)
__global__ __launch_bounds__(256) void softmax_k(
    const float* __restrict__ sc, unsigned short* __restrict__ attn)
{
    __shared__ float red[4];
    const int blk = blockIdx.x;              // b*120 + r
    const int b = blk / 120, r = blk % 120;
    const float* p = sc + (long)blk * 1024;
    const int t = threadIdx.x;
    float4 v = *(const float4*)&p[t * 4];

    float m = fmaxf(fmaxf(v.x, v.y), fmaxf(v.z, v.w));
#pragma unroll
    for (int o = 32; o; o >>= 1) m = fmaxf(m, __shfl_xor(m, o));
    if ((t & 63) == 0) red[t >> 6] = m;
    __syncthreads();
    m = fmaxf(fmaxf(red[0], red[1]), fmaxf(red[2], red[3]));
    __syncthreads();

    v.x = __expf(v.x - m); v.y = __expf(v.y - m);
    v.z = __expf(v.z - m); v.w = __expf(v.w - m);
    float s = v.x + v.y + v.z + v.w;
#pragma unroll
    for (int o = 32; o; o >>= 1) s += __shfl_xor(s, o);
    if ((t & 63) == 0) red[t >> 6] = s;
    __syncthreads();
    s = red[0] + red[1] + red[2] + red[3];
    const float inv = 1.0f / s;
    ushort4 o;
    o.x = f2bf(v.x * inv); o.y = f2bf(v.y * inv);
    o.z = f2bf(v.z * inv); o.w = f2bf(v.w * inv);
    *(ushort4*)&attn[(long)(b * 128 + r) * 1024 + t * 4] = o;
}

// ---------------- tail kernel: blocks [0,480) = edge head; [480,992) = energy12
__global__ __launch_bounds__(320) void tail_k(
    const float* __restrict__ hh, const float* __restrict__ b1,
    const float* __restrict__ W2, const float* __restrict__ b2,
    const float* __restrict__ enr, const int* __restrict__ nodes,
    const float* __restrict__ Wh1, const float* __restrict__ bh1,
    const float* __restrict__ Wh2, float* __restrict__ hidr,
    float* __restrict__ out)
{
    __shared__ float sm[8993];   // edge: hiS|b1S|hjS[15][257]|w2S[18][257]; energy: gf[1024]
    const int bid = blockIdx.x;
    const int t = threadIdx.x;

    if (bid < 480) {             // ---- edge: b = bid/15, i = bid%15
        const int b = bid / 15, i = bid % 15;
        float* hiS = sm;
        float* b1S = sm + 256;
        float* hjS = sm + 512;           // [15][257]
        float* w2S = sm + 512 + 3855;    // [18][257]
        const int j = t / 18, c = t % 18;
        float acc = 0.0f;

        for (int u0 = 0; u0 < 512; u0 += 256) {
            __syncthreads();
            if (t < 64) {
                float4 v = *(const float4*)&hh[(long)(b * 15 + i) * 1024 + u0 + t * 4];
                hiS[t * 4 + 0] = v.x; hiS[t * 4 + 1] = v.y;
                hiS[t * 4 + 2] = v.z; hiS[t * 4 + 3] = v.w;
            } else if (t < 128) {
                const int tt = t - 64;
                float4 v = *(const float4*)&b1[u0 + tt * 4];
                b1S[tt * 4 + 0] = v.x; b1S[tt * 4 + 1] = v.y;
                b1S[tt * 4 + 2] = v.z; b1S[tt * 4 + 3] = v.w;
            }
            for (int x = t; x < 960; x += 320) {
                const int r = x >> 6, cc = (x & 63) * 4;
                float4 v = *(const float4*)&hh[(long)(b * 15 + r) * 1024 + 512 + u0 + cc];
                hjS[r * 257 + cc + 0] = v.x; hjS[r * 257 + cc + 1] = v.y;
                hjS[r * 257 + cc + 2] = v.z; hjS[r * 257 + cc + 3] = v.w;
            }
            for (int x = t; x < 1152; x += 320) {
                const int r = x >> 6, cc = (x & 63) * 4;
                float4 v = *(const float4*)&W2[(long)r * 512 + u0 + cc];
                w2S[r * 257 + cc + 0] = v.x; w2S[r * 257 + cc + 1] = v.y;
                w2S[r * 257 + cc + 2] = v.z; w2S[r * 257 + cc + 3] = v.w;
            }
            __syncthreads();
            if (t < 270) {
                for (int u = 0; u < 256; ++u) {
                    float p = hiS[u] + hjS[j * 257 + u] + b1S[u];
                    p = p > 0.0f ? p : 0.0f;
                    acc += p * w2S[c * 257 + u];
                }
            }
        }
        if (t < 270)
            out[((long)(bid) * 15 + j) * 18 + c] = acc + b2[c];
    } else {                     // ---- energy12: z in [0,512)
        const int z = bid - 480;
        const int u0 = (z & 15) * 16;
        const int b  = z >> 4;
        float* gf = sm;

        int cnt = 0;
#pragma unroll
        for (int n = 0; n < 15; ++n) cnt += (nodes[b * 15 + n] != -1) ? 1 : 0;
        const float inv_valid = 1.0f / fmaxf((float)cnt, 1.0f);
        if (t < 256) {
            for (int e = t; e < 1024; e += 256) {
                float s = 0.0f;
#pragma unroll
                for (int n = 0; n < 15; ++n) {
                    const bool ok = nodes[b * 15 + n] != -1;
                    s += ok ? enr[(long)(b * 15 + n) * 1024 + e] : 0.0f;
                }
                gf[e] = s * inv_valid;
            }
        }
        __syncthreads();
        if (t < 256) {
            const int wave = t >> 6, lane = t & 63;
#pragma unroll
            for (int r = 0; r < 4; ++r) {
                const int u = u0 + wave * 4 + r;
                float s = 0.0f;
#pragma unroll
                for (int e0 = 0; e0 < 1024; e0 += 64)
                    s += gf[e0 + lane] * Wh1[(long)u * 1024 + e0 + lane];
#pragma unroll
                for (int o = 32; o; o >>= 1) s += __shfl_xor(s, o);
                if (lane == 0)
                    hidr[b * 256 + u] = fmaxf(s + bh1[u], 0.0f) * Wh2[u];
            }
        }
    }
}

// ---------------- energy stage 3
__global__ __launch_bounds__(256) void energy3_k(
    const float* __restrict__ hidr, const float* __restrict__ bh2,
    float* __restrict__ out)
{
    const int b = blockIdx.x;
    const int t = threadIdx.x;
    __shared__ float red[4];
    float v = hidr[b * 256 + t];
#pragma unroll
    for (int o = 32; o; o >>= 1) v += __shfl_xor(v, o);
    if ((t & 63) == 0) red[t >> 6] = v;
    __syncthreads();
    if (t == 0) out[129600 + b] = red[0] + red[1] + red[2] + red[3] + bh2[0];
}

// ---------------------------------------------------------------------------
extern "C" void kernel_launch(void* const* d_in, const int* in_sizes, int n_in,
                              void* d_out, int out_size, void* d_ws, size_t ws_size,
                              hipStream_t stream)
{
    const float* visual = (const float*)d_in[0];
    const int*   nodes  = (const int*)  d_in[1];
    const float* bboxes = (const float*)d_in[2];
    const float* emb    = (const float*)d_in[3];
    const float* Wb     = (const float*)d_in[4];
    const float* bb     = (const float*)d_in[5];
    const float* Wq     = (const float*)d_in[6];
    const float* bq     = (const float*)d_in[7];
    const float* Wk     = (const float*)d_in[8];
    /* bk (d_in[9]) cancels in softmax */
    const float* Wv     = (const float*)d_in[10];
    const float* bv     = (const float*)d_in[11];
    const float* Wo     = (const float*)d_in[12];
    const float* bo     = (const float*)d_in[13];
    const float* W1     = (const float*)d_in[14];
    const float* b1     = (const float*)d_in[15];
    const float* W2     = (const float*)d_in[16];
    const float* b2     = (const float*)d_in[17];
    const float* Wh1    = (const float*)d_in[18];
    const float* bh1    = (const float*)d_in[19];
    const float* Wh2    = (const float*)d_in[20];
    const float* bh2    = (const float*)d_in[21];

    float* out = (float*)d_out;
    float* ws  = (float*)d_ws;

    // workspace layout (offsets in fp32 words)
    unsigned short* query_bf = (unsigned short*)(ws);            // 512x1024 bf16
    unsigned short* q_bf     = (unsigned short*)(ws + 131072);   // 512x1024 bf16
    float* scores = ws + 262144;              // 32*120*1024 f32
    unsigned short* ctxf_bf  = (unsigned short*)(ws + 4194304);  // 32*120*1024 bf16
    unsigned short* ctx_bf   = (unsigned short*)(ws + 6160384);  // 512x1024 bf16
    float* enr    = ws + 6422528;             // 480*1024 f32
    unsigned short* enr_bf   = (unsigned short*)(ws + 6914048);  // 512x1024 bf16
    float* hh     = ws + 7176192;             // 480*1024 f32 (hi|hj)
    unsigned short* Wq_bf  = (unsigned short*)(ws + 7667712);    // 1024x1024 bf16
    unsigned short* Wo_bf  = (unsigned short*)(ws + 8192000);    // 1024x1024 bf16
    unsigned short* Wv_bf  = (unsigned short*)(ws + 8716288);    // 1024x1024 bf16
    unsigned short* W1r_bf = (unsigned short*)(ws + 9240576);    // 1024x1024 bf16
    unsigned short* WkT_bf = (unsigned short*)(ws + 9764864);    // 1024x1024 bf16
    unsigned short* qW_bf   = (unsigned short*)(ws + 10289152);  // 32*128*1024 bf16
    unsigned short* attn_bf = (unsigned short*)(ws + 12386304);  // 32*128*1024 bf16
    unsigned short* v_bfT   = (unsigned short*)(ws + 31260672);  // 32*1024*1024 bf16
    float* hidr   = ws + 48070656;            // 32*256

    const float inv_sqrt_hd = 0.08838834764831845f;  // 1/sqrt(128)
    const float* v_f = visual + 3 * 1048576;         // frame T-1; batch stride 4*1048576

    // 1) weight/query conversions
    uber_cvt_k<<<4832, 256, 0, stream>>>(
        nodes, bboxes, emb, Wb, bb, query_bf,
        Wq, Wo, Wv, W1, Wk, Wq_bf, Wo_bf, Wv_bf, W1r_bf, WkT_bf);

    // 2) q_bf = query_bf @ Wq_bf^T + bq   (MFMA, bf16-only out)
    pgemm_k<2><<<dim3(16, 8), 256, 0, stream>>>(
        query_bf, Wq_bf, bq, nullptr, q_bf, 480, 1024, 1024, 1024, 1024);

    // 3) qW_bf = (q_bf @ WkT_bf^T) * inv_sqrt_hd   (MFMA, batch (b,h))
    qw_k<<<dim3(4, 256), 256, 0, stream>>>(q_bf, WkT_bf, qW_bf, inv_sqrt_hd);

    // 4) scores[b] = qW_bf[b] @ bf16(v_f[b])^T   (on-the-fly B convert)
    sgemm_k<<<dim3(8, 2, 32), 256, 0, stream>>>(
        qW_bf, v_f, scores, 120, 131072, 4194304, 122880);

    // 4b) v_bfT transpose-convert (after scores: v_f now L3-warm)
    cvtT_k<<<dim3(16, 16, 32), 256, 0, stream>>>(v_f, v_bfT);

    // 5) softmax over l -> bf16 attn
    softmax_k<<<3840, 256, 0, stream>>>(scores, attn_bf);

    // 6) ctxf_bf[b] = attn[b] @ v_bfT[b]^T  (MFMA, bf16 out)
    bfgemm_k<<<dim3(8, 2, 32), 256, 0, stream>>>(
        attn_bf, v_bfT, ctxf_bf, 120, 131072, 1048576, 122880);

    // 7) ctx_bf = ctxf_bf @ Wv^T + bv      (MFMA, batch (b,h))
    ctx_k<<<256, 256, 0, stream>>>(ctxf_bf, Wv_bf, bv, ctx_bf);

    // 8) enr = ctx_bf @ Wo_bf^T + bo       (MFMA, dual out)
    pgemm_k<1><<<dim3(16, 8), 256, 0, stream>>>(
        ctx_bf, Wo_bf, bo, enr, enr_bf, 480, 1024, 1024, 1024, 1024);

    // 9) hh = enr_bf @ W1r_bf^T            (MFMA; cols 0..511 hi, 512..1023 hj)
    pgemm_k<0><<<dim3(16, 8), 256, 0, stream>>>(
        enr_bf, W1r_bf, nullptr, hh, nullptr, 480, 1024, 1024, 1024, 1024);

    // 10) edge + energy12 fused -> out[0..129600) and hidr
    tail_k<<<992, 320, 0, stream>>>(
        hh, b1, W2, b2, enr, nodes, Wh1, bh1, Wh2, hidr, out);

    // 11) energy -> out[129600 .. 129632)
    energy3_k<<<32, 256, 0, stream>>>(hidr, bh2, out);
}